// Round 1
// baseline (523.506 us; speedup 1.0000x reference)
//
#include <hip/hip_runtime.h>

// KiloNeRF fused MLP, fp32 baseline.
// Per point: h=relu(pts@w0+b0); h=relu(h@w1+b1); sigma=h@ws+bs;
// feat=h@wf+bf; hv=relu([feat,views]@wv+bv); rgb=hv@wr+br; out=[rgb,sigma].
// One thread per point. All weight accesses are uniform (unrolled literal
// indices) -> scalar loads; activations stay in VGPRs.

#define NPTS 4194304

__global__ __launch_bounds__(256) void kilonerf_fp32(
    const float* __restrict__ x,
    const float* __restrict__ w0, const float* __restrict__ b0,
    const float* __restrict__ w1, const float* __restrict__ b1,
    const float* __restrict__ wf, const float* __restrict__ bf,
    const float* __restrict__ ws, const float* __restrict__ bs,
    const float* __restrict__ wv, const float* __restrict__ bv,
    const float* __restrict__ wr, const float* __restrict__ br,
    float* __restrict__ out)
{
    const int i = blockIdx.x * blockDim.x + threadIdx.x;
    if (i >= NPTS) return;

    const float* xp = x + (size_t)i * 6;
    // 24B contiguous per lane; two dwordx2 + dwordx2 pattern is fine for L1.
    float p0 = xp[0], p1 = xp[1], p2 = xp[2];
    float v0 = xp[3], v1 = xp[4], v2 = xp[5];

    // layer 0: 3 -> 32, relu
    float h[32];
#pragma unroll
    for (int j = 0; j < 32; ++j) {
        float a = b0[j];
        a = fmaf(p0, w0[0 * 32 + j], a);
        a = fmaf(p1, w0[1 * 32 + j], a);
        a = fmaf(p2, w0[2 * 32 + j], a);
        h[j] = fmaxf(a, 0.f);
    }

    // layer 1: 32 -> 32, relu
    float h1[32];
#pragma unroll
    for (int j = 0; j < 32; ++j) {
        float a = b1[j];
#pragma unroll
        for (int k = 0; k < 32; ++k) a = fmaf(h[k], w1[k * 32 + j], a);
        h1[j] = fmaxf(a, 0.f);
    }

    // sigma: 32 -> 1 (no relu)
    float sigma = bs[0];
#pragma unroll
    for (int k = 0; k < 32; ++k) sigma = fmaf(h1[k], ws[k], sigma);

    // feature: 32 -> 32 (no relu)
    float feat[32];
#pragma unroll
    for (int j = 0; j < 32; ++j) {
        float a = bf[j];
#pragma unroll
        for (int k = 0; k < 32; ++k) a = fmaf(h1[k], wf[k * 32 + j], a);
        feat[j] = a;
    }

    // view layer: [feat(32), views(3)] -> 32, relu
    float hv[32];
#pragma unroll
    for (int j = 0; j < 32; ++j) {
        float a = bv[j];
#pragma unroll
        for (int k = 0; k < 32; ++k) a = fmaf(feat[k], wv[k * 32 + j], a);
        a = fmaf(v0, wv[32 * 32 + j], a);
        a = fmaf(v1, wv[33 * 32 + j], a);
        a = fmaf(v2, wv[34 * 32 + j], a);
        hv[j] = fmaxf(a, 0.f);
    }

    // rgb: 32 -> 3 (no relu)
    float r0 = br[0], r1 = br[1], r2 = br[2];
#pragma unroll
    for (int k = 0; k < 32; ++k) {
        r0 = fmaf(hv[k], wr[k * 3 + 0], r0);
        r1 = fmaf(hv[k], wr[k * 3 + 1], r1);
        r2 = fmaf(hv[k], wr[k * 3 + 2], r2);
    }

    reinterpret_cast<float4*>(out)[i] = make_float4(r0, r1, r2, sigma);
}

extern "C" void kernel_launch(void* const* d_in, const int* in_sizes, int n_in,
                              void* d_out, int out_size, void* d_ws, size_t ws_size,
                              hipStream_t stream) {
    const float* x  = (const float*)d_in[0];
    const float* w0 = (const float*)d_in[1];
    const float* b0 = (const float*)d_in[2];
    const float* w1 = (const float*)d_in[3];
    const float* b1 = (const float*)d_in[4];
    const float* wf = (const float*)d_in[5];
    const float* bf = (const float*)d_in[6];
    const float* ws = (const float*)d_in[7];
    const float* bs = (const float*)d_in[8];
    const float* wv = (const float*)d_in[9];
    const float* bv = (const float*)d_in[10];
    const float* wr = (const float*)d_in[11];
    const float* br = (const float*)d_in[12];
    float* out = (float*)d_out;

    dim3 block(256);
    dim3 grid(NPTS / 256);
    kilonerf_fp32<<<grid, block, 0, stream>>>(x, w0, b0, w1, b1, wf, bf,
                                              ws, bs, wv, bv, wr, br, out);
}

// Round 2
// 91.536 us; speedup vs baseline: 5.7191x; 5.7191x over previous
//
#include <hip/hip_runtime.h>

// KiloNeRF fused MLP — f16 MFMA version.
// Formulation: per 16-point tile, each layer is C = W^T(16xK) @ act(Kx16) via
// mfma_f32_16x16x32_f16, N = points. Activations stay lane-local across layers:
// we pick the positional k-map sigma(g,j) = (j<4 ? 4g+j : 16+4g+j-4) and load
// BOTH A (weights) and B (activations) with it, so any consistent HW wiring
// gives the correct dot products, and the C layout (col=lane&15=point,
// row=4*(lane>>4)+reg) feeds the next layer's B with zero cross-lane traffic.
// Layer 0 (3->32) is exact fp32 VALU; biases ride in the MFMA C operand.

#define NPTS  4194304
#define NTILES (NPTS / 16)

typedef _Float16 f16;
typedef _Float16 f16x8 __attribute__((ext_vector_type(8)));
typedef float    f32x4 __attribute__((ext_vector_type(4)));

#define MFMA(A, B, C) __builtin_amdgcn_mfma_f32_16x16x32_f16((A), (B), (C), 0, 0, 0)

__global__ __launch_bounds__(256) void kilonerf_mfma(
    const float* __restrict__ x,
    const float* __restrict__ w0, const float* __restrict__ b0,
    const float* __restrict__ w1, const float* __restrict__ b1,
    const float* __restrict__ wf, const float* __restrict__ bf,
    const float* __restrict__ ws, const float* __restrict__ bs,
    const float* __restrict__ wv, const float* __restrict__ bv,
    const float* __restrict__ wr, const float* __restrict__ br,
    float* __restrict__ out)
{
    const int lane = threadIdx.x & 63;
    const int g = lane >> 4;      // lane group 0..3
    const int c = lane & 15;      // column (point within tile) / row-of-A

    // positional k-map (same for A and B)
    int kk[8];
#pragma unroll
    for (int j = 0; j < 8; ++j) kk[j] = (j < 4) ? (4 * g + j) : (16 + 4 * g + (j - 4));

    // ---- one-time per-wave weight fragment gathers ----
    f16x8 aw1[2], awf[2], awv[2], awv2[2], aws, awr;
#pragma unroll
    for (int t = 0; t < 2; ++t) {
#pragma unroll
        for (int j = 0; j < 8; ++j) {
            const int m = c + 16 * t;
            aw1[t][j]  = (f16)w1[kk[j] * 32 + m];
            awf[t][j]  = (f16)wf[kk[j] * 32 + m];
            awv[t][j]  = (f16)wv[kk[j] * 32 + m];
            awv2[t][j] = (g == 0 && j < 3) ? (f16)wv[(32 + j) * 32 + m] : (f16)0.f;
        }
    }
#pragma unroll
    for (int j = 0; j < 8; ++j) {
        aws[j] = (c == 0) ? (f16)ws[kk[j]] : (f16)0.f;
        awr[j] = (c < 3) ? (f16)wr[kk[j] * 3 + c] : (f16)0.f;
    }

    // bias fragments (C-init): reg r corresponds to row 4g+r (+16t)
    f32x4 b1f[2], bff[2], bvf[2], brf, bsf;
#pragma unroll
    for (int t = 0; t < 2; ++t)
#pragma unroll
        for (int r = 0; r < 4; ++r) {
            const int m = 4 * g + r + 16 * t;
            b1f[t][r] = b1[m];
            bff[t][r] = bf[m];
            bvf[t][r] = bv[m];
        }
#pragma unroll
    for (int r = 0; r < 4; ++r) {
        brf[r] = (g == 0 && r < 3) ? br[r] : 0.f;
        bsf[r] = (g == 0 && r == 0) ? bs[0] : 0.f;
    }

    // layer-0 per-lane weights (fp32 exact): this lane's 8 k-slots
    float w0l[8][3], b0l[8];
#pragma unroll
    for (int j = 0; j < 8; ++j) {
        w0l[j][0] = w0[0 * 32 + kk[j]];
        w0l[j][1] = w0[1 * 32 + kk[j]];
        w0l[j][2] = w0[2 * 32 + kk[j]];
        b0l[j] = b0[kk[j]];
    }

    const int wslot  = blockIdx.x * 4 + (threadIdx.x >> 6);
    const int nslots = gridDim.x * 4;

    for (int tile = wslot; tile < NTILES; tile += nslots) {
        const int pbase = tile * 16;
        const float2* xp2 = reinterpret_cast<const float2*>(x + (size_t)(pbase + c) * 6);
        const float2 a0 = xp2[0], a1 = xp2[1], a2 = xp2[2];
        const float p0 = a0.x, p1 = a0.y, p2 = a1.x;
        const float v0 = a1.y, v1 = a2.x, v2 = a2.y;

        // ---- layer 0: 3 -> 32, relu (fp32 VALU) ----
        f16x8 bh0;
#pragma unroll
        for (int j = 0; j < 8; ++j) {
            float a = fmaf(p2, w0l[j][2], fmaf(p1, w0l[j][1], fmaf(p0, w0l[j][0], b0l[j])));
            bh0[j] = (f16)fmaxf(a, 0.f);
        }

        // ---- layer 1: 32 -> 32, relu ----
        f32x4 c10 = b1f[0], c11 = b1f[1];
        c10 = MFMA(aw1[0], bh0, c10);
        c11 = MFMA(aw1[1], bh0, c11);
        f16x8 bh1;
#pragma unroll
        for (int r = 0; r < 4; ++r) {
            bh1[r]     = (f16)fmaxf(c10[r], 0.f);
            bh1[4 + r] = (f16)fmaxf(c11[r], 0.f);
        }

        // ---- sigma: 32 -> 1 (row 0 of A valid) ----
        f32x4 cs = bsf;
        cs = MFMA(aws, bh1, cs);

        // ---- feature: 32 -> 32 (no relu) ----
        f32x4 cf0 = bff[0], cf1 = bff[1];
        cf0 = MFMA(awf[0], bh1, cf0);
        cf1 = MFMA(awf[1], bh1, cf1);
        f16x8 bft;
#pragma unroll
        for (int r = 0; r < 4; ++r) {
            bft[r]     = (f16)cf0[r];
            bft[4 + r] = (f16)cf1[r];
        }

        // ---- view layer: [feat(32), views(3)] -> 32, relu ----
        f16x8 bvw;
#pragma unroll
        for (int j = 0; j < 8; ++j) bvw[j] = (f16)0.f;
        if (g == 0) { bvw[0] = (f16)v0; bvw[1] = (f16)v1; bvw[2] = (f16)v2; }

        f32x4 cv0 = bvf[0], cv1 = bvf[1];
        cv0 = MFMA(awv[0], bft, cv0);
        cv1 = MFMA(awv[1], bft, cv1);
        cv0 = MFMA(awv2[0], bvw, cv0);
        cv1 = MFMA(awv2[1], bvw, cv1);
        f16x8 bhv;
#pragma unroll
        for (int r = 0; r < 4; ++r) {
            bhv[r]     = (f16)fmaxf(cv0[r], 0.f);
            bhv[4 + r] = (f16)fmaxf(cv1[r], 0.f);
        }

        // ---- rgb: 32 -> 3 (rows 0..2 of A valid) ----
        f32x4 cr = brf;
        cr = MFMA(awr, bhv, cr);

        // ---- store: lanes 0..15 hold rgb (regs 0..2) + sigma (reg 0) ----
        if (g == 0) {
            float4 o = make_float4(cr[0], cr[1], cr[2], cs[0]);
            *reinterpret_cast<float4*>(out + (size_t)(pbase + c) * 4) = o;
        }
    }
}

extern "C" void kernel_launch(void* const* d_in, const int* in_sizes, int n_in,
                              void* d_out, int out_size, void* d_ws, size_t ws_size,
                              hipStream_t stream) {
    const float* x  = (const float*)d_in[0];
    const float* w0 = (const float*)d_in[1];
    const float* b0 = (const float*)d_in[2];
    const float* w1 = (const float*)d_in[3];
    const float* b1 = (const float*)d_in[4];
    const float* wf = (const float*)d_in[5];
    const float* bf = (const float*)d_in[6];
    const float* ws = (const float*)d_in[7];
    const float* bs = (const float*)d_in[8];
    const float* wv = (const float*)d_in[9];
    const float* bv = (const float*)d_in[10];
    const float* wr = (const float*)d_in[11];
    const float* br = (const float*)d_in[12];
    float* out = (float*)d_out;

    dim3 block(256);
    dim3 grid(2048);
    kilonerf_mfma<<<grid, block, 0, stream>>>(x, w0, b0, w1, b1, wf, bf,
                                              ws, bs, wv, bv, wr, br, out);
}

// Round 3
// 86.324 us; speedup vs baseline: 6.0645x; 1.0604x over previous
//
#include <hip/hip_runtime.h>

// KiloNeRF fused MLP — f16 MFMA, 2-tile interleaved (ILP) version.
// Per 16-point tile each layer is C = W^T(16xK) @ act(Kx16) via
// mfma_f32_16x16x32_f16 (N = points). Positional k-map sigma(g,j) applied to
// BOTH A (weights) and B (activations) keeps activations lane-local across
// layers. Each wave processes TWO adjacent tiles stage-interleaved to give two
// independent dependency chains (latency hiding); weights/biases shared.

#define NPTS  4194304
#define NTILES (NPTS / 16)

typedef _Float16 f16;
typedef _Float16 f16x8 __attribute__((ext_vector_type(8)));
typedef float    f32x4 __attribute__((ext_vector_type(4)));

#define MFMA(A, B, C) __builtin_amdgcn_mfma_f32_16x16x32_f16((A), (B), (C), 0, 0, 0)

__global__ __launch_bounds__(256) void kilonerf_mfma2(
    const float* __restrict__ x,
    const float* __restrict__ w0, const float* __restrict__ b0,
    const float* __restrict__ w1, const float* __restrict__ b1,
    const float* __restrict__ wf, const float* __restrict__ bf,
    const float* __restrict__ ws, const float* __restrict__ bs,
    const float* __restrict__ wv, const float* __restrict__ bv,
    const float* __restrict__ wr, const float* __restrict__ br,
    float* __restrict__ out)
{
    const int lane = threadIdx.x & 63;
    const int g = lane >> 4;      // lane group 0..3
    const int c = lane & 15;      // column (point within tile) / row-of-A

    // positional k-map (same for A and B)
    int kk[8];
#pragma unroll
    for (int j = 0; j < 8; ++j) kk[j] = (j < 4) ? (4 * g + j) : (16 + 4 * g + (j - 4));

    // ---- one-time per-wave weight fragment gathers ----
    f16x8 aw1[2], awf[2], awv[2], awv2[2], aws, awr;
#pragma unroll
    for (int t = 0; t < 2; ++t) {
#pragma unroll
        for (int j = 0; j < 8; ++j) {
            const int m = c + 16 * t;
            aw1[t][j]  = (f16)w1[kk[j] * 32 + m];
            awf[t][j]  = (f16)wf[kk[j] * 32 + m];
            awv[t][j]  = (f16)wv[kk[j] * 32 + m];
            awv2[t][j] = (g == 0 && j < 3) ? (f16)wv[(32 + j) * 32 + m] : (f16)0.f;
        }
    }
#pragma unroll
    for (int j = 0; j < 8; ++j) {
        aws[j] = (c == 0) ? (f16)ws[kk[j]] : (f16)0.f;
        awr[j] = (c < 3) ? (f16)wr[kk[j] * 3 + c] : (f16)0.f;
    }

    // bias fragments (C-init): reg r corresponds to row 4g+r (+16t)
    f32x4 b1f[2], bff[2], bvf[2], brf, bsf;
#pragma unroll
    for (int t = 0; t < 2; ++t)
#pragma unroll
        for (int r = 0; r < 4; ++r) {
            const int m = 4 * g + r + 16 * t;
            b1f[t][r] = b1[m];
            bff[t][r] = bf[m];
            bvf[t][r] = bv[m];
        }
#pragma unroll
    for (int r = 0; r < 4; ++r) {
        brf[r] = (g == 0 && r < 3) ? br[r] : 0.f;
        bsf[r] = (g == 0 && r == 0) ? bs[0] : 0.f;
    }

    // layer-0 per-lane weights (fp32 exact): this lane's 8 k-slots
    float w0l[8][3], b0l[8];
#pragma unroll
    for (int j = 0; j < 8; ++j) {
        w0l[j][0] = w0[0 * 32 + kk[j]];
        w0l[j][1] = w0[1 * 32 + kk[j]];
        w0l[j][2] = w0[2 * 32 + kk[j]];
        b0l[j] = b0[kk[j]];
    }

    const int wslot  = blockIdx.x * 4 + (threadIdx.x >> 6);
    const int nslots = gridDim.x * 4;   // 8192 waves
    const int npairs = NTILES / 2;      // 131072

    for (int pair = wslot; pair < npairs; pair += nslots) {
        int pb[2];
        pb[0] = pair * 32;
        pb[1] = pair * 32 + 16;

        // ---- prefetch x for both tiles ----
        float p0[2], p1[2], p2[2], v0[2], v1[2], v2[2];
#pragma unroll
        for (int u = 0; u < 2; ++u) {
            const float2* xp2 = reinterpret_cast<const float2*>(x + (size_t)(pb[u] + c) * 6);
            const float2 a0 = xp2[0], a1 = xp2[1], a2 = xp2[2];
            p0[u] = a0.x; p1[u] = a0.y; p2[u] = a1.x;
            v0[u] = a1.y; v1[u] = a2.x; v2[u] = a2.y;
        }

        // ---- layer 0: 3 -> 32, relu (fp32 VALU) ----
        f16x8 bh0[2];
#pragma unroll
        for (int u = 0; u < 2; ++u)
#pragma unroll
            for (int j = 0; j < 8; ++j) {
                float a = fmaf(p2[u], w0l[j][2],
                          fmaf(p1[u], w0l[j][1],
                          fmaf(p0[u], w0l[j][0], b0l[j])));
                bh0[u][j] = (f16)fmaxf(a, 0.f);
            }

        // ---- layer 1: 32 -> 32, relu ----
        f32x4 c10[2], c11[2];
#pragma unroll
        for (int u = 0; u < 2; ++u) {
            c10[u] = MFMA(aw1[0], bh0[u], b1f[0]);
            c11[u] = MFMA(aw1[1], bh0[u], b1f[1]);
        }
        f16x8 bh1[2];
#pragma unroll
        for (int u = 0; u < 2; ++u)
#pragma unroll
            for (int r = 0; r < 4; ++r) {
                bh1[u][r]     = (f16)fmaxf(c10[u][r], 0.f);
                bh1[u][4 + r] = (f16)fmaxf(c11[u][r], 0.f);
            }

        // ---- sigma: 32 -> 1 (row 0 of A valid) ----
        f32x4 cs[2];
#pragma unroll
        for (int u = 0; u < 2; ++u) cs[u] = MFMA(aws, bh1[u], bsf);

        // ---- feature: 32 -> 32 (no relu) ----
        f32x4 cf0[2], cf1[2];
#pragma unroll
        for (int u = 0; u < 2; ++u) {
            cf0[u] = MFMA(awf[0], bh1[u], bff[0]);
            cf1[u] = MFMA(awf[1], bh1[u], bff[1]);
        }
        f16x8 bft[2];
#pragma unroll
        for (int u = 0; u < 2; ++u)
#pragma unroll
            for (int r = 0; r < 4; ++r) {
                bft[u][r]     = (f16)cf0[u][r];
                bft[u][4 + r] = (f16)cf1[u][r];
            }

        // ---- view layer: [feat(32), views(3)] -> 32, relu ----
        f16x8 bvw[2];
#pragma unroll
        for (int u = 0; u < 2; ++u) {
#pragma unroll
            for (int j = 0; j < 8; ++j) bvw[u][j] = (f16)0.f;
            if (g == 0) {
                bvw[u][0] = (f16)v0[u];
                bvw[u][1] = (f16)v1[u];
                bvw[u][2] = (f16)v2[u];
            }
        }
        f32x4 cv0[2], cv1[2];
#pragma unroll
        for (int u = 0; u < 2; ++u) {
            cv0[u] = MFMA(awv[0], bft[u], bvf[0]);
            cv1[u] = MFMA(awv[1], bft[u], bvf[1]);
            cv0[u] = MFMA(awv2[0], bvw[u], cv0[u]);
            cv1[u] = MFMA(awv2[1], bvw[u], cv1[u]);
        }
        f16x8 bhv[2];
#pragma unroll
        for (int u = 0; u < 2; ++u)
#pragma unroll
            for (int r = 0; r < 4; ++r) {
                bhv[u][r]     = (f16)fmaxf(cv0[u][r], 0.f);
                bhv[u][4 + r] = (f16)fmaxf(cv1[u][r], 0.f);
            }

        // ---- rgb: 32 -> 3 (rows 0..2 of A valid) ----
        f32x4 cr[2];
#pragma unroll
        for (int u = 0; u < 2; ++u) cr[u] = MFMA(awr, bhv[u], brf);

        // ---- store: lanes 0..15 hold rgb (regs 0..2) + sigma (reg 0) ----
        if (g == 0) {
#pragma unroll
            for (int u = 0; u < 2; ++u) {
                float4 o = make_float4(cr[u][0], cr[u][1], cr[u][2], cs[u][0]);
                *reinterpret_cast<float4*>(out + (size_t)(pb[u] + c) * 4) = o;
            }
        }
    }
}

extern "C" void kernel_launch(void* const* d_in, const int* in_sizes, int n_in,
                              void* d_out, int out_size, void* d_ws, size_t ws_size,
                              hipStream_t stream) {
    const float* x  = (const float*)d_in[0];
    const float* w0 = (const float*)d_in[1];
    const float* b0 = (const float*)d_in[2];
    const float* w1 = (const float*)d_in[3];
    const float* b1 = (const float*)d_in[4];
    const float* wf = (const float*)d_in[5];
    const float* bf = (const float*)d_in[6];
    const float* ws = (const float*)d_in[7];
    const float* bs = (const float*)d_in[8];
    const float* wv = (const float*)d_in[9];
    const float* bv = (const float*)d_in[10];
    const float* wr = (const float*)d_in[11];
    const float* br = (const float*)d_in[12];
    float* out = (float*)d_out;

    dim3 block(256);
    dim3 grid(2048);
    kilonerf_mfma2<<<grid, block, 0, stream>>>(x, w0, b0, w1, b1, wf, bf,
                                               ws, bs, wv, bv, wr, br, out);
}

// Round 5
// 84.465 us; speedup vs baseline: 6.1979x; 1.0220x over previous
//
#include <hip/hip_runtime.h>

// KiloNeRF fused MLP — f16 MFMA, packed-conversion (cvt_pkrtz) version.
// Formulation unchanged from R2/R3: per 16-point tile each layer is
// C = W^T(16xK) @ act(Kx16) via mfma_f32_16x16x32_f16; positional k-map
// sigma(g,j) applied to BOTH A (weights) and B (activations) keeps
// activations lane-local. R5 = R4 with the cvt_pkrtz return-type fix
// (__fp16 ext_vector, bit_cast to u32).
//  - all f32->f16 activation packing via v_cvt_pkrtz_f16_f32 word builds
//    (union H8), eliminating per-element cvt+insert VALU bloat
//  - cross-iteration prefetch of x
// Layer 0 stays exact fp32 FMA; weights are RTN-converted once at setup.

#define NPTS   4194304
#define NTILES (NPTS / 16)

typedef _Float16 f16;
typedef _Float16 f16x8 __attribute__((ext_vector_type(8)));
typedef float    f32x4 __attribute__((ext_vector_type(4)));

union H8 { f16x8 v; unsigned u[4]; };

static __device__ __forceinline__ unsigned pkrtz(float a, float b) {
    return __builtin_bit_cast(unsigned, __builtin_amdgcn_cvt_pkrtz(a, b));
}

#define MFMA(A, B, C) __builtin_amdgcn_mfma_f32_16x16x32_f16((A), (B), (C), 0, 0, 0)

__global__ __launch_bounds__(256) void kilonerf_pk(
    const float* __restrict__ x,
    const float* __restrict__ w0, const float* __restrict__ b0,
    const float* __restrict__ w1, const float* __restrict__ b1,
    const float* __restrict__ wf, const float* __restrict__ bf,
    const float* __restrict__ ws, const float* __restrict__ bs,
    const float* __restrict__ wv, const float* __restrict__ bv,
    const float* __restrict__ wr, const float* __restrict__ br,
    float* __restrict__ out)
{
    const int lane = threadIdx.x & 63;
    const int g = lane >> 4;      // lane group 0..3
    const int c = lane & 15;      // column (point within tile) / row-of-A

    // positional k-map (same for A and B)
    int kk[8];
#pragma unroll
    for (int j = 0; j < 8; ++j) kk[j] = (j < 4) ? (4 * g + j) : (16 + 4 * g + (j - 4));

    // ---- one-time per-wave weight fragment gathers (RTN) ----
    f16x8 aw1[2], awf[2], awv[2], awv2[2], aws, awr;
#pragma unroll
    for (int t = 0; t < 2; ++t) {
#pragma unroll
        for (int j = 0; j < 8; ++j) {
            const int m = c + 16 * t;
            aw1[t][j]  = (f16)w1[kk[j] * 32 + m];
            awf[t][j]  = (f16)wf[kk[j] * 32 + m];
            awv[t][j]  = (f16)wv[kk[j] * 32 + m];
            awv2[t][j] = (g == 0 && j < 3) ? (f16)wv[(32 + j) * 32 + m] : (f16)0.f;
        }
    }
#pragma unroll
    for (int j = 0; j < 8; ++j) {
        aws[j] = (c == 0) ? (f16)ws[kk[j]] : (f16)0.f;
        awr[j] = (c < 3) ? (f16)wr[kk[j] * 3 + c] : (f16)0.f;
    }

    // bias fragments (C-init): reg r corresponds to row 4g+r (+16t)
    f32x4 b1f[2], bff[2], bvf[2], brf, bsf;
#pragma unroll
    for (int t = 0; t < 2; ++t)
#pragma unroll
        for (int r = 0; r < 4; ++r) {
            const int m = 4 * g + r + 16 * t;
            b1f[t][r] = b1[m];
            bff[t][r] = bf[m];
            bvf[t][r] = bv[m];
        }
#pragma unroll
    for (int r = 0; r < 4; ++r) {
        brf[r] = (g == 0 && r < 3) ? br[r] : 0.f;
        bsf[r] = (g == 0 && r == 0) ? bs[0] : 0.f;
    }

    // layer-0 per-lane weights (fp32 exact): this lane's 8 k-slots
    float w0l[8][3], b0l[8];
#pragma unroll
    for (int j = 0; j < 8; ++j) {
        w0l[j][0] = w0[0 * 32 + kk[j]];
        w0l[j][1] = w0[1 * 32 + kk[j]];
        w0l[j][2] = w0[2 * 32 + kk[j]];
        b0l[j] = b0[kk[j]];
    }

    const int wslot  = blockIdx.x * 4 + (threadIdx.x >> 6);
    const int nslots = gridDim.x * 4;   // 8192 waves
    const int npairs = NTILES / 2;      // 131072

    // ---- prefetch first pair's x ----
    float2 nx[2][3];
#pragma unroll
    for (int u = 0; u < 2; ++u) {
        const float2* xp2 = reinterpret_cast<const float2*>(
            x + (size_t)(wslot * 32 + u * 16 + c) * 6);
        nx[u][0] = xp2[0]; nx[u][1] = xp2[1]; nx[u][2] = xp2[2];
    }

    for (int pair = wslot; pair < npairs; pair += nslots) {
        // unpack current x
        float p0[2], p1[2], p2[2], v0[2], v1[2], v2[2];
#pragma unroll
        for (int u = 0; u < 2; ++u) {
            p0[u] = nx[u][0].x; p1[u] = nx[u][0].y; p2[u] = nx[u][1].x;
            v0[u] = nx[u][1].y; v1[u] = nx[u][2].x; v2[u] = nx[u][2].y;
        }

        // issue next pair's loads (uniform clamp keeps addresses valid)
        int np = pair + nslots; if (np >= npairs) np = wslot;
#pragma unroll
        for (int u = 0; u < 2; ++u) {
            const float2* xp2 = reinterpret_cast<const float2*>(
                x + (size_t)(np * 32 + u * 16 + c) * 6);
            nx[u][0] = xp2[0]; nx[u][1] = xp2[1]; nx[u][2] = xp2[2];
        }

        // ---- layer 0: 3 -> 32, relu (fp32 FMA, pkrtz pack) ----
        H8 bh0[2];
#pragma unroll
        for (int u = 0; u < 2; ++u) {
            float a[8];
#pragma unroll
            for (int j = 0; j < 8; ++j)
                a[j] = fmaxf(fmaf(p2[u], w0l[j][2],
                             fmaf(p1[u], w0l[j][1],
                             fmaf(p0[u], w0l[j][0], b0l[j]))), 0.f);
            bh0[u].u[0] = pkrtz(a[0], a[1]);
            bh0[u].u[1] = pkrtz(a[2], a[3]);
            bh0[u].u[2] = pkrtz(a[4], a[5]);
            bh0[u].u[3] = pkrtz(a[6], a[7]);
        }

        // views fragment for the view layer (built early; independent)
        H8 bvw[2];
#pragma unroll
        for (int u = 0; u < 2; ++u) {
            bvw[u].u[0] = (g == 0) ? pkrtz(v0[u], v1[u]) : 0u;
            bvw[u].u[1] = (g == 0) ? pkrtz(v2[u], 0.f) : 0u;
            bvw[u].u[2] = 0u;
            bvw[u].u[3] = 0u;
        }

        // ---- layer 1: 32 -> 32, relu ----
        f32x4 c10[2], c11[2];
#pragma unroll
        for (int u = 0; u < 2; ++u) {
            c10[u] = MFMA(aw1[0], bh0[u].v, b1f[0]);
            c11[u] = MFMA(aw1[1], bh0[u].v, b1f[1]);
        }
        H8 bh1[2];
#pragma unroll
        for (int u = 0; u < 2; ++u) {
            bh1[u].u[0] = pkrtz(fmaxf(c10[u][0], 0.f), fmaxf(c10[u][1], 0.f));
            bh1[u].u[1] = pkrtz(fmaxf(c10[u][2], 0.f), fmaxf(c10[u][3], 0.f));
            bh1[u].u[2] = pkrtz(fmaxf(c11[u][0], 0.f), fmaxf(c11[u][1], 0.f));
            bh1[u].u[3] = pkrtz(fmaxf(c11[u][2], 0.f), fmaxf(c11[u][3], 0.f));
        }

        // ---- sigma: 32 -> 1 (row 0 of A valid) ----
        f32x4 cs[2];
#pragma unroll
        for (int u = 0; u < 2; ++u) cs[u] = MFMA(aws, bh1[u].v, bsf);

        // ---- feature: 32 -> 32 (no relu) ----
        f32x4 cf0[2], cf1[2];
#pragma unroll
        for (int u = 0; u < 2; ++u) {
            cf0[u] = MFMA(awf[0], bh1[u].v, bff[0]);
            cf1[u] = MFMA(awf[1], bh1[u].v, bff[1]);
        }
        H8 bft[2];
#pragma unroll
        for (int u = 0; u < 2; ++u) {
            bft[u].u[0] = pkrtz(cf0[u][0], cf0[u][1]);
            bft[u].u[1] = pkrtz(cf0[u][2], cf0[u][3]);
            bft[u].u[2] = pkrtz(cf1[u][0], cf1[u][1]);
            bft[u].u[3] = pkrtz(cf1[u][2], cf1[u][3]);
        }

        // ---- view layer: [feat(32), views(3)] -> 32, relu ----
        f32x4 cv0[2], cv1[2];
#pragma unroll
        for (int u = 0; u < 2; ++u) {
            cv0[u] = MFMA(awv[0], bft[u].v, bvf[0]);
            cv1[u] = MFMA(awv[1], bft[u].v, bvf[1]);
            cv0[u] = MFMA(awv2[0], bvw[u].v, cv0[u]);
            cv1[u] = MFMA(awv2[1], bvw[u].v, cv1[u]);
        }
        H8 bhv[2];
#pragma unroll
        for (int u = 0; u < 2; ++u) {
            bhv[u].u[0] = pkrtz(fmaxf(cv0[u][0], 0.f), fmaxf(cv0[u][1], 0.f));
            bhv[u].u[1] = pkrtz(fmaxf(cv0[u][2], 0.f), fmaxf(cv0[u][3], 0.f));
            bhv[u].u[2] = pkrtz(fmaxf(cv1[u][0], 0.f), fmaxf(cv1[u][1], 0.f));
            bhv[u].u[3] = pkrtz(fmaxf(cv1[u][2], 0.f), fmaxf(cv1[u][3], 0.f));
        }

        // ---- rgb: 32 -> 3 (rows 0..2 of A valid) ----
        f32x4 cr[2];
#pragma unroll
        for (int u = 0; u < 2; ++u) cr[u] = MFMA(awr, bhv[u].v, brf);

        // ---- store: lanes 0..15 hold rgb (regs 0..2) + sigma (reg 0) ----
        if (g == 0) {
#pragma unroll
            for (int u = 0; u < 2; ++u) {
                float4 o = make_float4(cr[u][0], cr[u][1], cr[u][2], cs[u][0]);
                *reinterpret_cast<float4*>(out + (size_t)(pair * 32 + u * 16 + c) * 4) = o;
            }
        }
    }
}

extern "C" void kernel_launch(void* const* d_in, const int* in_sizes, int n_in,
                              void* d_out, int out_size, void* d_ws, size_t ws_size,
                              hipStream_t stream) {
    const float* x  = (const float*)d_in[0];
    const float* w0 = (const float*)d_in[1];
    const float* b0 = (const float*)d_in[2];
    const float* w1 = (const float*)d_in[3];
    const float* b1 = (const float*)d_in[4];
    const float* wf = (const float*)d_in[5];
    const float* bf = (const float*)d_in[6];
    const float* ws = (const float*)d_in[7];
    const float* bs = (const float*)d_in[8];
    const float* wv = (const float*)d_in[9];
    const float* bv = (const float*)d_in[10];
    const float* wr = (const float*)d_in[11];
    const float* br = (const float*)d_in[12];
    float* out = (float*)d_out;

    dim3 block(256);
    dim3 grid(2048);
    kilonerf_pk<<<grid, block, 0, stream>>>(x, w0, b0, w1, b1, wf, bf,
                                            ws, bs, wv, bv, wr, br, out);
}

// Round 7
// 73.171 us; speedup vs baseline: 7.1546x; 1.1544x over previous
//
#include <hip/hip_runtime.h>

// KiloNeRF fused MLP — all-MFMA version.
// Per 16-point tile each layer is C = W^T(16xK) @ act(Kx16) via
// mfma_f32_16x16x32_f16; positional k-map sigma(g,j) on BOTH A and B keeps
// activations lane-local.
//  - layer 0 (3->32) as MFMA: A-fragment zero at k-slots>=3, so the pts
//    B-fragment needs no masking (0 * garbage == 0; all values finite).
//  - same garbage-slot trick removes cndmasks from the views fragment.
//  - relu in packed f16 (v_pk_max_f16 via __builtin_elementwise_max) after
//    pkrtz: relu and round-toward-zero commute, so this is exact wrt the
//    f16 pipeline.
//  - cross-iteration x prefetch retained.

#define NPTS   4194304
#define NTILES (NPTS / 16)

typedef _Float16 f16;
typedef _Float16 f16x2 __attribute__((ext_vector_type(2)));
typedef _Float16 f16x8 __attribute__((ext_vector_type(8)));
typedef float    f32x4 __attribute__((ext_vector_type(4)));

union H8 { f16x8 v; unsigned u[4]; };

static __device__ __forceinline__ unsigned pkrtz(float a, float b) {
    return __builtin_bit_cast(unsigned, __builtin_amdgcn_cvt_pkrtz(a, b));
}
static __device__ __forceinline__ unsigned relu2(unsigned w) {
    f16x2 h = __builtin_bit_cast(f16x2, w);
    f16x2 z = (f16x2)(f16)0.f;
    return __builtin_bit_cast(unsigned, __builtin_elementwise_max(h, z));
}

#define MFMA(A, B, C) __builtin_amdgcn_mfma_f32_16x16x32_f16((A), (B), (C), 0, 0, 0)

__global__ __launch_bounds__(256) void kilonerf_allmfma(
    const float* __restrict__ x,
    const float* __restrict__ w0, const float* __restrict__ b0,
    const float* __restrict__ w1, const float* __restrict__ b1,
    const float* __restrict__ wf, const float* __restrict__ bf,
    const float* __restrict__ ws, const float* __restrict__ bs,
    const float* __restrict__ wv, const float* __restrict__ bv,
    const float* __restrict__ wr, const float* __restrict__ br,
    float* __restrict__ out)
{
    const int lane = threadIdx.x & 63;
    const int g = lane >> 4;      // lane group 0..3
    const int c = lane & 15;      // column (point within tile) / row-of-A

    // positional k-map (same for A and B)
    int kk[8];
#pragma unroll
    for (int j = 0; j < 8; ++j) kk[j] = (j < 4) ? (4 * g + j) : (16 + 4 * g + (j - 4));

    // ---- one-time per-wave weight fragment gathers (RTN) ----
    f16x8 aw0[2], aw1[2], awf[2], awv[2], awv2[2], aws, awr;
#pragma unroll
    for (int t = 0; t < 2; ++t) {
#pragma unroll
        for (int j = 0; j < 8; ++j) {
            const int m = c + 16 * t;
            aw0[t][j]  = (kk[j] < 3) ? (f16)w0[kk[j] * 32 + m] : (f16)0.f;
            aw1[t][j]  = (f16)w1[kk[j] * 32 + m];
            awf[t][j]  = (f16)wf[kk[j] * 32 + m];
            awv[t][j]  = (f16)wv[kk[j] * 32 + m];
            awv2[t][j] = (kk[j] < 3) ? (f16)wv[(32 + kk[j]) * 32 + m] : (f16)0.f;
        }
    }
#pragma unroll
    for (int j = 0; j < 8; ++j) {
        aws[j] = (c == 0) ? (f16)ws[kk[j]] : (f16)0.f;
        awr[j] = (c < 3) ? (f16)wr[kk[j] * 3 + c] : (f16)0.f;
    }

    // bias fragments (C-init): reg r corresponds to row 4g+r (+16t)
    f32x4 b0f[2], b1f[2], bff[2], bvf[2], brf, bsf;
#pragma unroll
    for (int t = 0; t < 2; ++t)
#pragma unroll
        for (int r = 0; r < 4; ++r) {
            const int m = 4 * g + r + 16 * t;
            b0f[t][r] = b0[m];
            b1f[t][r] = b1[m];
            bff[t][r] = bf[m];
            bvf[t][r] = bv[m];
        }
#pragma unroll
    for (int r = 0; r < 4; ++r) {
        brf[r] = (g == 0 && r < 3) ? br[r] : 0.f;
        bsf[r] = (g == 0 && r == 0) ? bs[0] : 0.f;
    }

    const int wslot  = blockIdx.x * 4 + (threadIdx.x >> 6);
    const int nslots = gridDim.x * 4;   // 8192 waves
    const int npairs = NTILES / 2;      // 131072

    // ---- prefetch first pair's x ----
    float2 nx[2][3];
#pragma unroll
    for (int u = 0; u < 2; ++u) {
        const float2* xp2 = reinterpret_cast<const float2*>(
            x + (size_t)(wslot * 32 + u * 16 + c) * 6);
        nx[u][0] = xp2[0]; nx[u][1] = xp2[1]; nx[u][2] = xp2[2];
    }

    for (int pair = wslot; pair < npairs; pair += nslots) {
        // ---- build pts/views fragments from current x (garbage-slot trick:
        //      matching A-fragments are exactly zero at unused k-slots) ----
        H8 bp[2], bvw[2];
#pragma unroll
        for (int u = 0; u < 2; ++u) {
            bp[u].u[0]  = pkrtz(nx[u][0].x, nx[u][0].y);   // p0, p1
            bp[u].u[1]  = pkrtz(nx[u][1].x, nx[u][1].x);   // p2, (p2)
            bp[u].u[2]  = bp[u].u[0];
            bp[u].u[3]  = bp[u].u[1];
            bvw[u].u[0] = pkrtz(nx[u][1].y, nx[u][2].x);   // v0, v1
            bvw[u].u[1] = pkrtz(nx[u][2].y, nx[u][2].y);   // v2, (v2)
            bvw[u].u[2] = bvw[u].u[0];
            bvw[u].u[3] = bvw[u].u[1];
        }

        // issue next pair's loads (wraps to a valid address on last iter)
        int np = pair + nslots; if (np >= npairs) np = wslot;
#pragma unroll
        for (int u = 0; u < 2; ++u) {
            const float2* xp2 = reinterpret_cast<const float2*>(
                x + (size_t)(np * 32 + u * 16 + c) * 6);
            nx[u][0] = xp2[0]; nx[u][1] = xp2[1]; nx[u][2] = xp2[2];
        }

        // ---- layer 0: 3 -> 32, relu (MFMA) ----
        f32x4 c00[2], c01[2];
#pragma unroll
        for (int u = 0; u < 2; ++u) {
            c00[u] = MFMA(aw0[0], bp[u].v, b0f[0]);
            c01[u] = MFMA(aw0[1], bp[u].v, b0f[1]);
        }
        H8 bh0[2];
#pragma unroll
        for (int u = 0; u < 2; ++u) {
            bh0[u].u[0] = relu2(pkrtz(c00[u][0], c00[u][1]));
            bh0[u].u[1] = relu2(pkrtz(c00[u][2], c00[u][3]));
            bh0[u].u[2] = relu2(pkrtz(c01[u][0], c01[u][1]));
            bh0[u].u[3] = relu2(pkrtz(c01[u][2], c01[u][3]));
        }

        // ---- layer 1: 32 -> 32, relu ----
        f32x4 c10[2], c11[2];
#pragma unroll
        for (int u = 0; u < 2; ++u) {
            c10[u] = MFMA(aw1[0], bh0[u].v, b1f[0]);
            c11[u] = MFMA(aw1[1], bh0[u].v, b1f[1]);
        }
        H8 bh1[2];
#pragma unroll
        for (int u = 0; u < 2; ++u) {
            bh1[u].u[0] = relu2(pkrtz(c10[u][0], c10[u][1]));
            bh1[u].u[1] = relu2(pkrtz(c10[u][2], c10[u][3]));
            bh1[u].u[2] = relu2(pkrtz(c11[u][0], c11[u][1]));
            bh1[u].u[3] = relu2(pkrtz(c11[u][2], c11[u][3]));
        }

        // ---- sigma: 32 -> 1 (row 0 of A valid) ----
        f32x4 cs[2];
#pragma unroll
        for (int u = 0; u < 2; ++u) cs[u] = MFMA(aws, bh1[u].v, bsf);

        // ---- feature: 32 -> 32 (no relu) ----
        f32x4 cf0[2], cf1[2];
#pragma unroll
        for (int u = 0; u < 2; ++u) {
            cf0[u] = MFMA(awf[0], bh1[u].v, bff[0]);
            cf1[u] = MFMA(awf[1], bh1[u].v, bff[1]);
        }
        H8 bft[2];
#pragma unroll
        for (int u = 0; u < 2; ++u) {
            bft[u].u[0] = pkrtz(cf0[u][0], cf0[u][1]);
            bft[u].u[1] = pkrtz(cf0[u][2], cf0[u][3]);
            bft[u].u[2] = pkrtz(cf1[u][0], cf1[u][1]);
            bft[u].u[3] = pkrtz(cf1[u][2], cf1[u][3]);
        }

        // ---- view layer: [feat(32), views(3)] -> 32, relu ----
        f32x4 cv0[2], cv1[2];
#pragma unroll
        for (int u = 0; u < 2; ++u) {
            cv0[u] = MFMA(awv[0], bft[u].v, bvf[0]);
            cv1[u] = MFMA(awv[1], bft[u].v, bvf[1]);
            cv0[u] = MFMA(awv2[0], bvw[u].v, cv0[u]);
            cv1[u] = MFMA(awv2[1], bvw[u].v, cv1[u]);
        }
        H8 bhv[2];
#pragma unroll
        for (int u = 0; u < 2; ++u) {
            bhv[u].u[0] = relu2(pkrtz(cv0[u][0], cv0[u][1]));
            bhv[u].u[1] = relu2(pkrtz(cv0[u][2], cv0[u][3]));
            bhv[u].u[2] = relu2(pkrtz(cv1[u][0], cv1[u][1]));
            bhv[u].u[3] = relu2(pkrtz(cv1[u][2], cv1[u][3]));
        }

        // ---- rgb: 32 -> 3 (rows 0..2 of A valid) ----
        f32x4 cr[2];
#pragma unroll
        for (int u = 0; u < 2; ++u) cr[u] = MFMA(awr, bhv[u].v, brf);

        // ---- store: lanes 0..15 hold rgb (regs 0..2) + sigma (reg 0) ----
        if (g == 0) {
#pragma unroll
            for (int u = 0; u < 2; ++u) {
                float4 o = make_float4(cr[u][0], cr[u][1], cr[u][2], cs[u][0]);
                *reinterpret_cast<float4*>(out + (size_t)(pair * 32 + u * 16 + c) * 4) = o;
            }
        }
    }
}

extern "C" void kernel_launch(void* const* d_in, const int* in_sizes, int n_in,
                              void* d_out, int out_size, void* d_ws, size_t ws_size,
                              hipStream_t stream) {
    const float* x  = (const float*)d_in[0];
    const float* w0 = (const float*)d_in[1];
    const float* b0 = (const float*)d_in[2];
    const float* w1 = (const float*)d_in[3];
    const float* b1 = (const float*)d_in[4];
    const float* wf = (const float*)d_in[5];
    const float* bf = (const float*)d_in[6];
    const float* ws = (const float*)d_in[7];
    const float* bs = (const float*)d_in[8];
    const float* wv = (const float*)d_in[9];
    const float* bv = (const float*)d_in[10];
    const float* wr = (const float*)d_in[11];
    const float* br = (const float*)d_in[12];
    float* out = (float*)d_out;

    dim3 block(256);
    dim3 grid(2048);
    kilonerf_allmfma<<<grid, block, 0, stream>>>(x, w0, b0, w1, b1, wf, bf,
                                                 ws, bs, wv, bv, wr, br, out);
}

// Round 8
// 61.840 us; speedup vs baseline: 8.4655x; 1.1832x over previous
//
#include <hip/hip_runtime.h>

// KiloNeRF fused MLP — all-MFMA, occupancy-tuned version.
// Per 16-point tile each layer is C = W^T(16xK) @ act(Kx16) via
// mfma_f32_16x16x32_f16; positional k-map sigma(g,j) on BOTH A and B keeps
// activations lane-local. R8 changes (target: cross the 128-reg/4-wave cliff):
//  - __launch_bounds__(256, 4): force allocator to 4 waves/SIMD.
//  - homogeneous-bias fold: slot k=3 of the pts fragment carries 1.0 and
//    aw0's k=3 row carries b0 (same for views/awv2 <- bv) -> zero C-init,
//    kills b0f/bvf (16 regs), and view layer loses one dependent stage.
//  - no x prefetch buffer (TLP hides it at 4 waves/SIMD).

#define NPTS   4194304
#define NTILES (NPTS / 16)

typedef _Float16 f16;
typedef _Float16 f16x2 __attribute__((ext_vector_type(2)));
typedef _Float16 f16x8 __attribute__((ext_vector_type(8)));
typedef float    f32x4 __attribute__((ext_vector_type(4)));

union H8 { f16x8 v; unsigned u[4]; };

static __device__ __forceinline__ unsigned pkrtz(float a, float b) {
    return __builtin_bit_cast(unsigned, __builtin_amdgcn_cvt_pkrtz(a, b));
}
static __device__ __forceinline__ unsigned relu2(unsigned w) {
    f16x2 h = __builtin_bit_cast(f16x2, w);
    f16x2 z = (f16x2)(f16)0.f;
    return __builtin_bit_cast(unsigned, __builtin_elementwise_max(h, z));
}

#define MFMA(A, B, C) __builtin_amdgcn_mfma_f32_16x16x32_f16((A), (B), (C), 0, 0, 0)

__global__ __launch_bounds__(256, 4) void kilonerf_occ(
    const float* __restrict__ x,
    const float* __restrict__ w0, const float* __restrict__ b0,
    const float* __restrict__ w1, const float* __restrict__ b1,
    const float* __restrict__ wf, const float* __restrict__ bf,
    const float* __restrict__ ws, const float* __restrict__ bs,
    const float* __restrict__ wv, const float* __restrict__ bv,
    const float* __restrict__ wr, const float* __restrict__ br,
    float* __restrict__ out)
{
    const int lane = threadIdx.x & 63;
    const int g = lane >> 4;      // lane group 0..3
    const int c = lane & 15;      // column (point within tile) / row-of-A

    // positional k-map (same for A and B)
    int kk[8];
#pragma unroll
    for (int j = 0; j < 8; ++j) kk[j] = (j < 4) ? (4 * g + j) : (16 + 4 * g + (j - 4));

    // ---- one-time per-wave weight fragment gathers (RTN) ----
    // aw0 row k=3 carries b0 (homogeneous input 1.0 in pts slot 3);
    // awv2 row k=3 carries bv (homogeneous 1.0 in views slot 3).
    f16x8 aw0[2], aw1[2], awf[2], awv[2], awv2[2], aws, awr;
#pragma unroll
    for (int t = 0; t < 2; ++t) {
#pragma unroll
        for (int j = 0; j < 8; ++j) {
            const int m = c + 16 * t;
            aw0[t][j]  = (kk[j] < 3) ? (f16)w0[kk[j] * 32 + m]
                        : (kk[j] == 3 ? (f16)b0[m] : (f16)0.f);
            aw1[t][j]  = (f16)w1[kk[j] * 32 + m];
            awf[t][j]  = (f16)wf[kk[j] * 32 + m];
            awv[t][j]  = (f16)wv[kk[j] * 32 + m];
            awv2[t][j] = (kk[j] < 3) ? (f16)wv[(32 + kk[j]) * 32 + m]
                        : (kk[j] == 3 ? (f16)bv[m] : (f16)0.f);
        }
    }
#pragma unroll
    for (int j = 0; j < 8; ++j) {
        aws[j] = (c == 0) ? (f16)ws[kk[j]] : (f16)0.f;
        awr[j] = (c < 3) ? (f16)wr[kk[j] * 3 + c] : (f16)0.f;
    }

    // remaining bias C-inits (full-K layers have no spare slots)
    f32x4 b1f[2], bff[2], brf, bsf;
#pragma unroll
    for (int t = 0; t < 2; ++t)
#pragma unroll
        for (int r = 0; r < 4; ++r) {
            const int m = 4 * g + r + 16 * t;
            b1f[t][r] = b1[m];
            bff[t][r] = bf[m];
        }
#pragma unroll
    for (int r = 0; r < 4; ++r) {
        brf[r] = (g == 0 && r < 3) ? br[r] : 0.f;
        bsf[r] = (g == 0 && r == 0) ? bs[0] : 0.f;
    }
    const f32x4 zf = {0.f, 0.f, 0.f, 0.f};

    const int wslot  = blockIdx.x * 4 + (threadIdx.x >> 6);
    const int nslots = gridDim.x * 4;   // 8192 waves
    const int npairs = NTILES / 2;      // 131072

    for (int pair = wslot; pair < npairs; pair += nslots) {
        // ---- load x, build pts/views fragments (garbage-slot trick:
        //      matching A-fragments are exactly zero at unused k-slots;
        //      slot k=3 carries the homogeneous 1.0) ----
        H8 bp[2], bvw[2];
#pragma unroll
        for (int u = 0; u < 2; ++u) {
            const float2* xp2 = reinterpret_cast<const float2*>(
                x + (size_t)(pair * 32 + u * 16 + c) * 6);
            const float2 a0 = xp2[0], a1 = xp2[1], a2 = xp2[2];
            bp[u].u[0]  = pkrtz(a0.x, a0.y);    // p0, p1
            bp[u].u[1]  = pkrtz(a1.x, 1.0f);    // p2, 1.0 (bias slot)
            bp[u].u[2]  = 0u;
            bp[u].u[3]  = 0u;
            bvw[u].u[0] = pkrtz(a1.y, a2.x);    // v0, v1
            bvw[u].u[1] = pkrtz(a2.y, 1.0f);    // v2, 1.0 (bias slot)
            bvw[u].u[2] = 0u;
            bvw[u].u[3] = 0u;
        }

        // ---- layer 0: 3 -> 32 (+bias via slot 3), relu (MFMA) ----
        f32x4 c00[2], c01[2];
#pragma unroll
        for (int u = 0; u < 2; ++u) {
            c00[u] = MFMA(aw0[0], bp[u].v, zf);
            c01[u] = MFMA(aw0[1], bp[u].v, zf);
        }
        H8 bh0[2];
#pragma unroll
        for (int u = 0; u < 2; ++u) {
            bh0[u].u[0] = relu2(pkrtz(c00[u][0], c00[u][1]));
            bh0[u].u[1] = relu2(pkrtz(c00[u][2], c00[u][3]));
            bh0[u].u[2] = relu2(pkrtz(c01[u][0], c01[u][1]));
            bh0[u].u[3] = relu2(pkrtz(c01[u][2], c01[u][3]));
        }

        // ---- view partial: views(3)+bv via slot 3 (independent of main chain) ----
        f32x4 cv0[2], cv1[2];
#pragma unroll
        for (int u = 0; u < 2; ++u) {
            cv0[u] = MFMA(awv2[0], bvw[u].v, zf);
            cv1[u] = MFMA(awv2[1], bvw[u].v, zf);
        }

        // ---- layer 1: 32 -> 32, relu ----
        f32x4 c10[2], c11[2];
#pragma unroll
        for (int u = 0; u < 2; ++u) {
            c10[u] = MFMA(aw1[0], bh0[u].v, b1f[0]);
            c11[u] = MFMA(aw1[1], bh0[u].v, b1f[1]);
        }
        H8 bh1[2];
#pragma unroll
        for (int u = 0; u < 2; ++u) {
            bh1[u].u[0] = relu2(pkrtz(c10[u][0], c10[u][1]));
            bh1[u].u[1] = relu2(pkrtz(c10[u][2], c10[u][3]));
            bh1[u].u[2] = relu2(pkrtz(c11[u][0], c11[u][1]));
            bh1[u].u[3] = relu2(pkrtz(c11[u][2], c11[u][3]));
        }

        // ---- sigma: 32 -> 1 (row 0 of A valid) ----
        f32x4 cs[2];
#pragma unroll
        for (int u = 0; u < 2; ++u) cs[u] = MFMA(aws, bh1[u].v, bsf);

        // ---- feature: 32 -> 32 (no relu) ----
        f32x4 cf0[2], cf1[2];
#pragma unroll
        for (int u = 0; u < 2; ++u) {
            cf0[u] = MFMA(awf[0], bh1[u].v, bff[0]);
            cf1[u] = MFMA(awf[1], bh1[u].v, bff[1]);
        }
        H8 bft[2];
#pragma unroll
        for (int u = 0; u < 2; ++u) {
            bft[u].u[0] = pkrtz(cf0[u][0], cf0[u][1]);
            bft[u].u[1] = pkrtz(cf0[u][2], cf0[u][3]);
            bft[u].u[2] = pkrtz(cf1[u][0], cf1[u][1]);
            bft[u].u[3] = pkrtz(cf1[u][2], cf1[u][3]);
        }

        // ---- view layer: accumulate feat into the views partial, relu ----
#pragma unroll
        for (int u = 0; u < 2; ++u) {
            cv0[u] = MFMA(awv[0], bft[u].v, cv0[u]);
            cv1[u] = MFMA(awv[1], bft[u].v, cv1[u]);
        }
        H8 bhv[2];
#pragma unroll
        for (int u = 0; u < 2; ++u) {
            bhv[u].u[0] = relu2(pkrtz(cv0[u][0], cv0[u][1]));
            bhv[u].u[1] = relu2(pkrtz(cv0[u][2], cv0[u][3]));
            bhv[u].u[2] = relu2(pkrtz(cv1[u][0], cv1[u][1]));
            bhv[u].u[3] = relu2(pkrtz(cv1[u][2], cv1[u][3]));
        }

        // ---- rgb: 32 -> 3 (rows 0..2 of A valid) ----
        f32x4 cr[2];
#pragma unroll
        for (int u = 0; u < 2; ++u) cr[u] = MFMA(awr, bhv[u].v, brf);

        // ---- store: lanes 0..15 hold rgb (regs 0..2) + sigma (reg 0) ----
        if (g == 0) {
#pragma unroll
            for (int u = 0; u < 2; ++u) {
                float4 o = make_float4(cr[u][0], cr[u][1], cr[u][2], cs[u][0]);
                *reinterpret_cast<float4*>(out + (size_t)(pair * 32 + u * 16 + c) * 4) = o;
            }
        }
    }
}

extern "C" void kernel_launch(void* const* d_in, const int* in_sizes, int n_in,
                              void* d_out, int out_size, void* d_ws, size_t ws_size,
                              hipStream_t stream) {
    const float* x  = (const float*)d_in[0];
    const float* w0 = (const float*)d_in[1];
    const float* b0 = (const float*)d_in[2];
    const float* w1 = (const float*)d_in[3];
    const float* b1 = (const float*)d_in[4];
    const float* wf = (const float*)d_in[5];
    const float* bf = (const float*)d_in[6];
    const float* ws = (const float*)d_in[7];
    const float* bs = (const float*)d_in[8];
    const float* wv = (const float*)d_in[9];
    const float* bv = (const float*)d_in[10];
    const float* wr = (const float*)d_in[11];
    const float* br = (const float*)d_in[12];
    float* out = (float*)d_out;

    dim3 block(256);
    dim3 grid(2048);
    kilonerf_occ<<<grid, block, 0, stream>>>(x, w0, b0, w1, b1, wf, bf,
                                             ws, bs, wv, bv, wr, br, out);
}